// Round 1
// baseline (469.544 us; speedup 1.0000x reference)
//
#include <hip/hip_runtime.h>
#include <stdint.h>

#define NN   8192
#define IND  256
#define HID  16
#define KN   6
#define CH   512      // j-rows staged per LDS chunk
#define RPW  4        // rows per wave in k2

__device__ __forceinline__ uint64_t kmax(uint64_t a, uint64_t b) { return a > b ? a : b; }
__device__ __forceinline__ uint64_t kmin(uint64_t a, uint64_t b) { return a < b ? a : b; }

// ---------------------------------------------------------------------------
// k1: h[i] = normalize(x[i] @ W^T + b), also zero rs[i].
// One wave per row; lane handles 4 contiguous input features (float4).
// ---------------------------------------------------------------------------
__global__ __launch_bounds__(256) void k1_embed(const float* __restrict__ x,
                                                const float* __restrict__ W,
                                                const float* __restrict__ b,
                                                float* __restrict__ h,
                                                float* __restrict__ rs)
{
    const int lane = threadIdx.x & 63;
    const int wv   = threadIdx.x >> 6;
    const int row  = blockIdx.x * 4 + wv;

    const float4 xv = *(const float4*)(x + (size_t)row * IND + lane * 4);

    float acc[HID];
#pragma unroll
    for (int k = 0; k < HID; ++k) {
        const float4 wv4 = *(const float4*)(W + (size_t)k * IND + lane * 4);
        float v = xv.x * wv4.x + xv.y * wv4.y + xv.z * wv4.z + xv.w * wv4.w;
#pragma unroll
        for (int m = 32; m >= 1; m >>= 1) v += __shfl_xor(v, m, 64);
        acc[k] = v;
    }

    if (lane == 0) {
        float hv[HID];
        float ss = 0.f;
#pragma unroll
        for (int k = 0; k < HID; ++k) { hv[k] = acc[k] + b[k]; ss += hv[k] * hv[k]; }
        const float nrm = fmaxf(sqrtf(ss), 1e-12f);
#pragma unroll
        for (int k = 0; k < HID; ++k) hv[k] = hv[k] / nrm;
        float4* hp = (float4*)(h + (size_t)row * HID);
        hp[0] = make_float4(hv[0],  hv[1],  hv[2],  hv[3]);
        hp[1] = make_float4(hv[4],  hv[5],  hv[6],  hv[7]);
        hp[2] = make_float4(hv[8],  hv[9],  hv[10], hv[11]);
        hp[3] = make_float4(hv[12], hv[13], hv[14], hv[15]);
        rs[row] = 0.f;
    }
}

// ---------------------------------------------------------------------------
// k2: fused sim row scan + top-7 (incl. self, self dropped as rank 0).
// Block = 256 threads = 4 waves; each wave owns RPW=4 rows; LDS stages CH=512
// candidate rows per chunk. Keys: (flip(f32) << 32) | ~j  -> uint64 max-order
// == (value desc, index asc), matching jax.lax.top_k tie-breaking.
// ---------------------------------------------------------------------------
__global__ __launch_bounds__(256) void k2_topk(const float* __restrict__ h,
                                               int* __restrict__ nbr_idx,
                                               float* __restrict__ nbr_val)
{
    __shared__ float lds[CH][HID];   // 32 KB, row-major

    const int tid  = threadIdx.x;
    const int lane = tid & 63;
    const int wv   = tid >> 6;
    const int row0 = blockIdx.x * (4 * RPW) + wv * RPW;

    // wave's row vectors (wave-uniform)
    float hr[RPW][HID];
#pragma unroll
    for (int r = 0; r < RPW; ++r) {
        const float4* hp = (const float4*)(h + (size_t)(row0 + r) * HID);
        const float4 t0 = hp[0], t1 = hp[1], t2 = hp[2], t3 = hp[3];
        hr[r][0]=t0.x;  hr[r][1]=t0.y;  hr[r][2]=t0.z;  hr[r][3]=t0.w;
        hr[r][4]=t1.x;  hr[r][5]=t1.y;  hr[r][6]=t1.z;  hr[r][7]=t1.w;
        hr[r][8]=t2.x;  hr[r][9]=t2.y;  hr[r][10]=t2.z; hr[r][11]=t2.w;
        hr[r][12]=t3.x; hr[r][13]=t3.y; hr[r][14]=t3.z; hr[r][15]=t3.w;
    }

    uint64_t lst[RPW][8];
#pragma unroll
    for (int r = 0; r < RPW; ++r)
#pragma unroll
        for (int t = 0; t < 8; ++t) lst[r][t] = 0ull;

    for (int cb = 0; cb < NN; cb += CH) {
        __syncthreads();
        // stage CH rows x 16 floats = 2048 float4s, 8 per thread, coalesced
#pragma unroll
        for (int it = 0; it < (CH * HID / 4) / 256; ++it) {
            const int flat = it * 256 + tid;
            const int j = flat >> 2, q = flat & 3;
            *(float4*)&lds[j][q * 4] = *(const float4*)(h + (size_t)(cb + j) * HID + q * 4);
        }
        __syncthreads();

#pragma unroll
        for (int g = 0; g < CH / 64; ++g) {
            const int jr = g * 64 + lane;
            const float4 a0 = *(const float4*)&lds[jr][0];
            const float4 a1 = *(const float4*)&lds[jr][4];
            const float4 a2 = *(const float4*)&lds[jr][8];
            const float4 a3 = *(const float4*)&lds[jr][12];
            const uint32_t ikey = ~(uint32_t)(cb + jr);
#pragma unroll
            for (int r = 0; r < RPW; ++r) {
                float v = hr[r][0]*a0.x  + hr[r][1]*a0.y  + hr[r][2]*a0.z  + hr[r][3]*a0.w
                        + hr[r][4]*a1.x  + hr[r][5]*a1.y  + hr[r][6]*a1.z  + hr[r][7]*a1.w
                        + hr[r][8]*a2.x  + hr[r][9]*a2.y  + hr[r][10]*a2.z + hr[r][11]*a2.w
                        + hr[r][12]*a3.x + hr[r][13]*a3.y + hr[r][14]*a3.z + hr[r][15]*a3.w;
                uint32_t u = __float_as_uint(v);
                u = (u & 0x80000000u) ? ~u : (u | 0x80000000u);
                const uint64_t key = ((uint64_t)u << 32) | (uint64_t)ikey;
                if (key > lst[r][7]) {            // enters top-8
                    lst[r][7] = key;
#pragma unroll
                    for (int s = 7; s >= 1; --s) { // bubble up, keeps sorted desc
                        const uint64_t hi = kmax(lst[r][s - 1], lst[r][s]);
                        const uint64_t lo = kmin(lst[r][s - 1], lst[r][s]);
                        lst[r][s - 1] = hi; lst[r][s] = lo;
                    }
                }
            }
        }
    }

    // cross-lane butterfly merge: after 6 steps every lane holds wave top-8
#pragma unroll
    for (int r = 0; r < RPW; ++r) {
#pragma unroll
        for (int m = 1; m < 64; m <<= 1) {
            uint64_t o[8];
#pragma unroll
            for (int t = 0; t < 8; ++t)
                o[t] = (uint64_t)__shfl_xor((unsigned long long)lst[r][t], m, 64);
            uint64_t X[8];
#pragma unroll
            for (int t = 0; t < 8; ++t) X[t] = kmax(lst[r][t], o[7 - t]);  // half-cleaner
            // bitonic merge (desc), static indices only
#define CSWP(i, jx) { const uint64_t hi = kmax(X[i], X[jx]); const uint64_t lo = kmin(X[i], X[jx]); X[i] = hi; X[jx] = lo; }
            CSWP(0,4) CSWP(1,5) CSWP(2,6) CSWP(3,7)
            CSWP(0,2) CSWP(1,3) CSWP(4,6) CSWP(5,7)
            CSWP(0,1) CSWP(2,3) CSWP(4,5) CSWP(6,7)
#undef CSWP
#pragma unroll
            for (int t = 0; t < 8; ++t) lst[r][t] = X[t];
        }
    }

    if (lane == 0) {
#pragma unroll
        for (int r = 0; r < RPW; ++r) {
            const int row = row0 + r;
#pragma unroll
            for (int t = 1; t <= KN; ++t) {        // ranks 1..6 (rank 0 = self)
                const uint64_t k = lst[r][t];
                uint32_t u = (uint32_t)(k >> 32);
                u = (u & 0x80000000u) ? (u & 0x7fffffffu) : ~u;   // un-flip
                nbr_val[(size_t)row * KN + (t - 1)] = __uint_as_float(u);
                nbr_idx[(size_t)row * KN + (t - 1)] = (int)~(uint32_t)k;
            }
        }
    }
}

// ---------------------------------------------------------------------------
// k3: zero-fill d_out (64M floats as 16M float4s, exact cover)
// ---------------------------------------------------------------------------
__global__ __launch_bounds__(256) void k3_zero(float4* __restrict__ out)
{
    const size_t i = (size_t)blockIdx.x * 256 + threadIdx.x;
    out[i] = make_float4(0.f, 0.f, 0.f, 0.f);
}

// ---------------------------------------------------------------------------
// k4: rs[i] = row sums of symmetrized sparse matrix (atomic accumulate)
// ---------------------------------------------------------------------------
__global__ __launch_bounds__(256) void k4_rowsum(const int* __restrict__ nbr_idx,
                                                 const float* __restrict__ nbr_val,
                                                 float* __restrict__ rs)
{
    const int e = blockIdx.x * 256 + threadIdx.x;   // < NN*KN
    const int i = e / KN;
    const int j = nbr_idx[e];
    const float v = nbr_val[e] * 0.5f;
    atomicAdd(&rs[i], v);
    atomicAdd(&rs[j], v);
}

// ---------------------------------------------------------------------------
// k5: scatter final normalized values into pre-zeroed dense output
// out[i][j] = 0.5*(A_ij + A_ji) / (rs[i] + 1e-8); atomics handle the case
// where both directed edges exist.
// ---------------------------------------------------------------------------
__global__ __launch_bounds__(256) void k5_scatter(const int* __restrict__ nbr_idx,
                                                  const float* __restrict__ nbr_val,
                                                  const float* __restrict__ rs,
                                                  float* __restrict__ out)
{
    const int e = blockIdx.x * 256 + threadIdx.x;   // < NN*KN
    const int i = e / KN;
    const int j = nbr_idx[e];
    const float v = nbr_val[e] * 0.5f;
    const float wi = v / (rs[i] + 1e-8f);
    const float wj = v / (rs[j] + 1e-8f);
    atomicAdd(out + (size_t)i * NN + j, wi);
    atomicAdd(out + (size_t)j * NN + i, wj);
}

// ---------------------------------------------------------------------------
extern "C" void kernel_launch(void* const* d_in, const int* in_sizes, int n_in,
                              void* d_out, int out_size, void* d_ws, size_t ws_size,
                              hipStream_t stream)
{
    const float* x = (const float*)d_in[0];   // 8192 x 256
    const float* W = (const float*)d_in[1];   // 16 x 256
    const float* b = (const float*)d_in[2];   // 16
    float* out = (float*)d_out;               // 8192 x 8192

    // workspace layout (~950 KB)
    float* h  = (float*)d_ws;                       // NN*HID
    float* rs = h + (size_t)NN * HID;               // NN
    float* nv = rs + NN;                            // NN*KN
    int*   ni = (int*)(nv + (size_t)NN * KN);       // NN*KN

    k1_embed <<<NN / 4,               256, 0, stream>>>(x, W, b, h, rs);
    k2_topk  <<<NN / (4 * RPW),       256, 0, stream>>>(h, ni, nv);
    k3_zero  <<<(int)(((size_t)NN * NN / 4) / 256), 256, 0, stream>>>((float4*)out);
    k4_rowsum<<<(NN * KN) / 256,      256, 0, stream>>>(ni, nv, rs);
    k5_scatter<<<(NN * KN) / 256,     256, 0, stream>>>(ni, nv, rs, out);
}